// Round 2
// baseline (1256.251 us; speedup 1.0000x reference)
//
#include <hip/hip_runtime.h>
#include <hip/hip_bf16.h>
#include <stdint.h>

#define LN_EPS 1e-5f

typedef __attribute__((ext_vector_type(8))) __bf16 bf16x8;
typedef __attribute__((ext_vector_type(8))) short short8;
typedef __attribute__((ext_vector_type(4))) float floatx4;

__device__ __forceinline__ ushort f2bf(float f) {
    __hip_bfloat16 h = __float2bfloat16(f);
    return *reinterpret_cast<ushort*>(&h);
}
__device__ __forceinline__ float bf2f(ushort u) {
    __hip_bfloat16 h = *reinterpret_cast<__hip_bfloat16*>(&u);
    return __bfloat162float(h);
}

// async global->LDS, 16B per lane; LDS dest = wave-uniform base + lane*16
// (holds because lds offset == chunk index * 16 in thread order). m97 pattern.
__device__ __forceinline__ void gload16(const void* g, void* l) {
#if __has_builtin(__builtin_amdgcn_global_load_lds)
    __builtin_amdgcn_global_load_lds(
        (const __attribute__((address_space(1))) unsigned int*)g,
        (__attribute__((address_space(3))) unsigned int*)l, 16, 0, 0);
#else
    *(int4*)l = *(const int4*)g;
#endif
}

// ---------------------------------------------------------------------------
// GEMM: C[M,N] = A[M,K](bf16 rm, lda) x Bt[N,K](bf16 rm, ldb)  (Bt = B^T)
// 128x128 tile, BK=32, 256 thr (4 waves 2x2 of 64x64), mfma 16x16x32 bf16.
// EPI: 0 bf16 store | 1 bf16 sigmoid | 2 bf16 relu^2 | 3 f32 out=add0+mul0*acc
// ---------------------------------------------------------------------------
template <int EPI>
__global__ __launch_bounds__(256, 2) void gemm_bt(
    const ushort* __restrict__ A, const ushort* __restrict__ Bt,
    int N, int K, int lda, int ldb, int ldc,
    float* __restrict__ outF, ushort* __restrict__ outB,
    const float* __restrict__ add0, const ushort* __restrict__ mul0) {
    __shared__ __align__(16) ushort As[128 * 32];
    __shared__ __align__(16) ushort Bs[128 * 32];

    const int tid  = threadIdx.x;
    const int lane = tid & 63;
    const int wv   = tid >> 6;
    const int quad = lane >> 4;
    const int l16  = lane & 15;
    const int wm   = (wv >> 1) * 64;
    const int wn   = (wv & 1) * 64;
    const long m0 = (long)blockIdx.y * 128;
    const long n0 = (long)blockIdx.x * 128;

    floatx4 acc[4][4];
#pragma unroll
    for (int i = 0; i < 4; i++)
#pragma unroll
        for (int j = 0; j < 4; j++) acc[i][j] = (floatx4)0.f;

    // staging: 512 chunks x 16B per tile; each thread DMAs 2 for A, 2 for B
    const int ci0 = tid, ci1 = tid + 256;
    const int r0 = ci0 >> 2, kc0 = (ci0 & 3) * 8;
    const int r1 = ci1 >> 2, kc1 = (ci1 & 3) * 8;
    const ushort* Ab0 = A + (m0 + r0) * (long)lda + kc0;
    const ushort* Ab1 = A + (m0 + r1) * (long)lda + kc1;
    const ushort* Bb0 = Bt + (n0 + r0) * (long)ldb + kc0;
    const ushort* Bb1 = Bt + (n0 + r1) * (long)ldb + kc1;

    for (int k0 = 0; k0 < K; k0 += 32) {
        gload16(Ab0 + k0, &As[ci0 * 8]);
        gload16(Ab1 + k0, &As[ci1 * 8]);
        gload16(Bb0 + k0, &Bs[ci0 * 8]);
        gload16(Bb1 + k0, &Bs[ci1 * 8]);
        __syncthreads();

        bf16x8 a[4], b[4];
#pragma unroll
        for (int mi = 0; mi < 4; mi++)
            a[mi] = __builtin_bit_cast(
                bf16x8, *(const short8*)&As[(wm + mi * 16 + l16) * 32 + quad * 8]);
#pragma unroll
        for (int ni = 0; ni < 4; ni++)
            b[ni] = __builtin_bit_cast(
                bf16x8, *(const short8*)&Bs[(wn + ni * 16 + l16) * 32 + quad * 8]);
#pragma unroll
        for (int mi = 0; mi < 4; mi++)
#pragma unroll
            for (int ni = 0; ni < 4; ni++)
                acc[mi][ni] = __builtin_amdgcn_mfma_f32_16x16x32_bf16(
                    a[mi], b[ni], acc[mi][ni], 0, 0, 0);
        __syncthreads();
    }

    // C/D layout: col = lane&15, row = quad*4 + reg (m89/m91-verified)
#pragma unroll
    for (int mi = 0; mi < 4; mi++) {
#pragma unroll
        for (int ni = 0; ni < 4; ni++) {
#pragma unroll
            for (int r = 0; r < 4; r++) {
                long m = m0 + wm + mi * 16 + quad * 4 + r;
                long n = n0 + wn + ni * 16 + l16;
                long idx = m * (long)ldc + n;
                float v = acc[mi][ni][r];
                if constexpr (EPI == 0) {
                    outB[idx] = f2bf(v);
                } else if constexpr (EPI == 1) {
                    outB[idx] = f2bf(1.f / (1.f + __expf(-v)));
                } else if constexpr (EPI == 2) {
                    float t = fmaxf(v, 0.f);
                    outB[idx] = f2bf(t * t);
                } else {
                    outF[idx] = add0[idx] + bf2f(mul0[idx]) * v;
                }
            }
        }
    }
}

// ---------------------------------------------------------------------------
// Fused LayerNorm + time-shift + mix -> bf16 outputs (2 or 3 mixes).
// One block per token row; computes LN of row and row-1 (zero h_prev at t==0).
// ---------------------------------------------------------------------------
template <int NMIX>
__global__ __launch_bounds__(256) void ln_mix(
    const float* __restrict__ x, const float* __restrict__ g,
    const float* __restrict__ be,
    const float* __restrict__ mx0, const float* __restrict__ mx1,
    const float* __restrict__ mx2,
    ushort* __restrict__ o0, ushort* __restrict__ o1, ushort* __restrict__ o2,
    int T, int C) {
    const long row = blockIdx.x;
    const int t = (int)(row % T);
    const int tid = threadIdx.x;
    const int i0 = tid * 4;

    floatx4 xc = *(const floatx4*)&x[row * C + i0];
    floatx4 xp = (floatx4)0.f;
    if (t > 0) xp = *(const floatx4*)&x[(row - 1) * C + i0];

    float sc = xc.x + xc.y + xc.z + xc.w;
    float qc = xc.x * xc.x + xc.y * xc.y + xc.z * xc.z + xc.w * xc.w;
    float sp = xp.x + xp.y + xp.z + xp.w;
    float qp = xp.x * xp.x + xp.y * xp.y + xp.z * xp.z + xp.w * xp.w;

#pragma unroll
    for (int off = 32; off; off >>= 1) {
        sc += __shfl_xor(sc, off);
        qc += __shfl_xor(qc, off);
        sp += __shfl_xor(sp, off);
        qp += __shfl_xor(qp, off);
    }
    __shared__ float part[4][4];
    const int wv = tid >> 6;
    if ((tid & 63) == 0) {
        part[wv][0] = sc; part[wv][1] = qc; part[wv][2] = sp; part[wv][3] = qp;
    }
    __syncthreads();
    sc = part[0][0] + part[1][0] + part[2][0] + part[3][0];
    qc = part[0][1] + part[1][1] + part[2][1] + part[3][1];
    sp = part[0][2] + part[1][2] + part[2][2] + part[3][2];
    qp = part[0][3] + part[1][3] + part[2][3] + part[3][3];

    const float invC = 1.f / (float)C;
    float muc = sc * invC;
    float rsc = rsqrtf(qc * invC - muc * muc + LN_EPS);
    float mup = sp * invC;
    float rsp = rsqrtf(qp * invC - mup * mup + LN_EPS);

    floatx4 gv = *(const floatx4*)&g[i0];
    floatx4 bv = *(const floatx4*)&be[i0];
    floatx4 hc = (xc - muc) * rsc * gv + bv;
    floatx4 hp = (floatx4)0.f;
    if (t > 0) hp = (xp - mup) * rsp * gv + bv;

    {
        floatx4 mk = *(const floatx4*)&mx0[i0];
        floatx4 v = hc * mk + hp * (1.f - mk);
        ushort4 pk;
        pk.x = f2bf(v.x); pk.y = f2bf(v.y); pk.z = f2bf(v.z); pk.w = f2bf(v.w);
        *(ushort4*)&o0[row * C + i0] = pk;
    }
    {
        floatx4 mk = *(const floatx4*)&mx1[i0];
        floatx4 v = hc * mk + hp * (1.f - mk);
        ushort4 pk;
        pk.x = f2bf(v.x); pk.y = f2bf(v.y); pk.z = f2bf(v.z); pk.w = f2bf(v.w);
        *(ushort4*)&o1[row * C + i0] = pk;
    }
    if constexpr (NMIX == 3) {
        floatx4 mk = *(const floatx4*)&mx2[i0];
        floatx4 v = hc * mk + hp * (1.f - mk);
        ushort4 pk;
        pk.x = f2bf(v.x); pk.y = f2bf(v.y); pk.z = f2bf(v.z); pk.w = f2bf(v.w);
        *(ushort4*)&o2[row * C + i0] = pk;
    }
}

// ---------------------------------------------------------------------------
// WKV scan fused with residual combine: out = x + r * wkv(w,u,k,v).
// One thread per (b,c) channel, sequential over T. k,v,r are bf16.
// ---------------------------------------------------------------------------
__global__ __launch_bounds__(256) void wkv_scan(
    const float* __restrict__ w, const float* __restrict__ u,
    const ushort* __restrict__ k, const ushort* __restrict__ v,
    const ushort* __restrict__ r, const float* __restrict__ x,
    float* __restrict__ out, int T, int C) {
    const int gc = blockIdx.x * 256 + threadIdx.x;
    const int b = gc / C;
    const int c = gc - b * C;
    const float ww = w[c], uu = u[c];
    const long base = (long)b * T * C + c;
    const ushort* kp = k + base;
    const ushort* vp = v + base;
    const ushort* rp = r + base;
    const float* xp_ = x + base;
    float* op = out + base;

    float aa = 0.f, pp = -1e38f;
#pragma unroll 4
    for (int t = 0; t < T; ++t) {
        const long o = (long)t * C;
        float kk = bf2f(kp[o]);
        float vv = bf2f(vp[o]);
        float p = fmaxf(pp, uu + kk);
        float e1 = __expf(pp - p);
        float e2 = __expf(uu + kk - p);
        float y = __fdividef(e1 * aa + e2 * vv, e1 + e2);
        op[o] = xp_[o] + bf2f(rp[o]) * y;
        float p2 = fmaxf(pp + ww, ww + kk);
        float e1u = __expf(pp + ww - p2);
        float e2u = __expf(ww + kk - p2);
        float aa2 = e1u * aa + e2u * vv;
        float bb2 = e1u + e2u;
        pp = p2 + __logf(bb2);
        aa = aa2;
    }
}

// out[n][k] = bf16(in[k][n]); in is [K][N] fp32 row-major. block (32,8).
__global__ __launch_bounds__(256) void transpose_bf16(
    const float* __restrict__ in, ushort* __restrict__ out, int K, int N) {
    __shared__ float tile[32][33];
    const int tx = threadIdx.x, ty = threadIdx.y;
    const long k0 = (long)blockIdx.y * 32, n0 = (long)blockIdx.x * 32;
#pragma unroll
    for (int i = 0; i < 4; i++)
        tile[ty + i * 8][tx] = in[(k0 + ty + i * 8) * N + n0 + tx];
    __syncthreads();
#pragma unroll
    for (int i = 0; i < 4; i++)
        out[(n0 + ty + i * 8) * K + k0 + tx] = f2bf(tile[tx][ty + i * 8]);
}

extern "C" void kernel_launch(void* const* d_in, const int* in_sizes, int n_in,
                              void* d_out, int out_size, void* d_ws, size_t ws_size,
                              hipStream_t stream) {
    const float* x      = (const float*)d_in[0];
    const float* tdecay = (const float*)d_in[1];
    const float* tfirst = (const float*)d_in[2];
    const float* w_tk   = (const float*)d_in[3];
    const float* w_tv   = (const float*)d_in[4];
    const float* w_tr   = (const float*)d_in[5];
    const float* w_ck   = (const float*)d_in[6];
    const float* w_cv   = (const float*)d_in[7];
    const float* w_cr   = (const float*)d_in[8];
    const float* ln1g   = (const float*)d_in[9];
    const float* ln1b   = (const float*)d_in[10];
    const float* ln2g   = (const float*)d_in[11];
    const float* ln2b   = (const float*)d_in[12];
    const float* mixk   = (const float*)d_in[13];
    const float* mixv   = (const float*)d_in[14];
    const float* mixr   = (const float*)d_in[15];
    const float* cmixk  = (const float*)d_in[16];
    const float* cmixr  = (const float*)d_in[17];
    float* out = (float*)d_out;

    const int C  = in_sizes[1];              // 1024
    const long M = (long)in_sizes[0] / C;    // 16384
    const int T  = 2048;
    const int B  = (int)(M / T);
    const int H  = 2 * C;                    // 2048 = half of 4C

    // workspace layout (MB offsets), total requirement 184 MB with reuse:
    //  0 wT_tk(2) 2 wT_tv(2) 4 wT_tr(2) 6 wT_cr(2) 8 wT_ck(8) 16 wT_cv0(4) 20 wT_cv1(4)
    // 24: xk    -> rbuf -> scr            (32)
    // 56: xv    -> ck                     (32)
    // 88: xr    -> cr -> kkhalf[88..152]  (64)
    // 120: kbuf (32)  [inside kk region, dead before kk written]
    // 152: vbuf (32)
    const size_t MBy = 1024ull * 1024ull;
    char* w8 = (char*)d_ws;
    ushort* wT_tk  = (ushort*)(w8 + 0 * MBy);
    ushort* wT_tv  = (ushort*)(w8 + 2 * MBy);
    ushort* wT_tr  = (ushort*)(w8 + 4 * MBy);
    ushort* wT_cr  = (ushort*)(w8 + 6 * MBy);
    ushort* wT_ck  = (ushort*)(w8 + 8 * MBy);    // [4096][1024]
    ushort* wT_cv0 = (ushort*)(w8 + 16 * MBy);   // [1024][2048]
    ushort* wT_cv1 = (ushort*)(w8 + 20 * MBy);   // [1024][2048]
    ushort* xk     = (ushort*)(w8 + 24 * MBy);
    ushort* xv     = (ushort*)(w8 + 56 * MBy);
    ushort* xr     = (ushort*)(w8 + 88 * MBy);
    ushort* kbuf   = (ushort*)(w8 + 120 * MBy);
    ushort* vbuf   = (ushort*)(w8 + 152 * MBy);
    ushort* rbuf   = (ushort*)(w8 + 24 * MBy);   // xk dead
    ushort* ck     = (ushort*)(w8 + 56 * MBy);   // xv dead
    ushort* cr     = (ushort*)(w8 + 88 * MBy);   // xr dead
    ushort* scr    = (ushort*)(w8 + 24 * MBy);   // rbuf dead
    ushort* kkbuf  = (ushort*)(w8 + 88 * MBy);   // cr/kbuf dead; 64MB

    dim3 tb(32, 8);
    transpose_bf16<<<dim3(C / 32, C / 32), tb, 0, stream>>>(w_tk, wT_tk, C, C);
    transpose_bf16<<<dim3(C / 32, C / 32), tb, 0, stream>>>(w_tv, wT_tv, C, C);
    transpose_bf16<<<dim3(C / 32, C / 32), tb, 0, stream>>>(w_tr, wT_tr, C, C);
    transpose_bf16<<<dim3(C / 32, C / 32), tb, 0, stream>>>(w_cr, wT_cr, C, C);
    transpose_bf16<<<dim3(4 * C / 32, C / 32), tb, 0, stream>>>(w_ck, wT_ck, C, 4 * C);
    transpose_bf16<<<dim3(C / 32, H / 32), tb, 0, stream>>>(w_cv, wT_cv0, H, C);
    transpose_bf16<<<dim3(C / 32, H / 32), tb, 0, stream>>>(w_cv + (long)H * C, wT_cv1, H, C);

    ln_mix<3><<<(int)M, 256, 0, stream>>>(x, ln1g, ln1b, mixk, mixv, mixr,
                                          xk, xv, xr, T, C);

    dim3 gsq(C / 128, (int)(M / 128));
    gemm_bt<0><<<gsq, 256, 0, stream>>>(xk, wT_tk, C, C, C, C, C,
                                        nullptr, kbuf, nullptr, nullptr);
    gemm_bt<0><<<gsq, 256, 0, stream>>>(xv, wT_tv, C, C, C, C, C,
                                        nullptr, vbuf, nullptr, nullptr);
    gemm_bt<1><<<gsq, 256, 0, stream>>>(xr, wT_tr, C, C, C, C, C,
                                        nullptr, rbuf, nullptr, nullptr);

    wkv_scan<<<(B * C) / 256, 256, 0, stream>>>(tdecay, tfirst, kbuf, vbuf,
                                                rbuf, x, out, T, C);

    ln_mix<2><<<(int)M, 256, 0, stream>>>(out, ln2g, ln2b, cmixk, cmixr, nullptr,
                                          ck, cr, nullptr, T, C);

    gemm_bt<1><<<gsq, 256, 0, stream>>>(cr, wT_cr, C, C, C, C, C,
                                        nullptr, scr, nullptr, nullptr);

    // channel-mix hidden (4C) processed in two 2C halves through one 64MB buffer
    for (int h = 0; h < 2; ++h) {
        const ushort* wck_h = wT_ck + (long)h * H * C;   // rows [h*2C, h*2C+2C)
        const ushort* wcv_h = (h == 0) ? wT_cv0 : wT_cv1;
        gemm_bt<2><<<dim3(H / 128, (int)(M / 128)), 256, 0, stream>>>(
            ck, wck_h, H, C, C, C, H, nullptr, kkbuf, nullptr, nullptr);
        gemm_bt<3><<<gsq, 256, 0, stream>>>(
            kkbuf, wcv_h, C, H, H, H, C, out, nullptr, out, scr);
    }
}

// Round 3
// 1123.110 us; speedup vs baseline: 1.1185x; 1.1185x over previous
//
#include <hip/hip_runtime.h>
#include <hip/hip_bf16.h>
#include <stdint.h>

#define LN_EPS 1e-5f

typedef __attribute__((ext_vector_type(8))) __bf16 bf16x8;
typedef __attribute__((ext_vector_type(8))) short short8;
typedef __attribute__((ext_vector_type(4))) float floatx4;

__device__ __forceinline__ ushort f2bf(float f) {
    __hip_bfloat16 h = __float2bfloat16(f);
    return *reinterpret_cast<ushort*>(&h);
}
__device__ __forceinline__ float bf2f(ushort u) {
    return __builtin_bit_cast(float, ((unsigned int)u) << 16);
}

// async global->LDS, 16B per lane; LDS dest = wave-uniform base + lane*16
__device__ __forceinline__ void gload16(const void* g, void* l) {
#if __has_builtin(__builtin_amdgcn_global_load_lds)
    __builtin_amdgcn_global_load_lds(
        (const __attribute__((address_space(1))) unsigned int*)g,
        (__attribute__((address_space(3))) unsigned int*)l, 16, 0, 0);
#else
    *(int4*)l = *(const int4*)g;
#endif
}

// ---------------------------------------------------------------------------
// GEMM: C[M,N] = A[M,K](bf16 rm, lda) x Bt[N,K](bf16 rm, ldb)  (Bt = B^T)
// 128x128 tile, BK=32, 256 thr (4 waves 2x2 of 64x64), mfma 16x16x32 bf16.
// EPI: 0 bf16 | 1 bf16 sigmoid | 2 bf16 relu^2 | 3 f32 out=add0+mul0*acc
//      4 bf16 transposed (idx = n*ldc + m) | 5 bf16 sigmoid transposed
// ---------------------------------------------------------------------------
template <int EPI>
__global__ __launch_bounds__(256, 2) void gemm_bt(
    const ushort* __restrict__ A, const ushort* __restrict__ Bt,
    int N, int K, int lda, int ldb, int ldc,
    float* __restrict__ outF, ushort* __restrict__ outB,
    const float* __restrict__ add0, const ushort* __restrict__ mul0) {
    __shared__ __align__(16) ushort As[128 * 32];
    __shared__ __align__(16) ushort Bs[128 * 32];

    const int tid  = threadIdx.x;
    const int lane = tid & 63;
    const int wv   = tid >> 6;
    const int quad = lane >> 4;
    const int l16  = lane & 15;
    const int wm   = (wv >> 1) * 64;
    const int wn   = (wv & 1) * 64;
    const long m0 = (long)blockIdx.y * 128;
    const long n0 = (long)blockIdx.x * 128;

    floatx4 acc[4][4];
#pragma unroll
    for (int i = 0; i < 4; i++)
#pragma unroll
        for (int j = 0; j < 4; j++) acc[i][j] = (floatx4)0.f;

    const int ci0 = tid, ci1 = tid + 256;
    const int r0 = ci0 >> 2, kc0 = (ci0 & 3) * 8;
    const int r1 = ci1 >> 2, kc1 = (ci1 & 3) * 8;
    const ushort* Ab0 = A + (m0 + r0) * (long)lda + kc0;
    const ushort* Ab1 = A + (m0 + r1) * (long)lda + kc1;
    const ushort* Bb0 = Bt + (n0 + r0) * (long)ldb + kc0;
    const ushort* Bb1 = Bt + (n0 + r1) * (long)ldb + kc1;

    for (int k0 = 0; k0 < K; k0 += 32) {
        gload16(Ab0 + k0, &As[ci0 * 8]);
        gload16(Ab1 + k0, &As[ci1 * 8]);
        gload16(Bb0 + k0, &Bs[ci0 * 8]);
        gload16(Bb1 + k0, &Bs[ci1 * 8]);
        __syncthreads();

        bf16x8 a[4], b[4];
#pragma unroll
        for (int mi = 0; mi < 4; mi++)
            a[mi] = __builtin_bit_cast(
                bf16x8, *(const short8*)&As[(wm + mi * 16 + l16) * 32 + quad * 8]);
#pragma unroll
        for (int ni = 0; ni < 4; ni++)
            b[ni] = __builtin_bit_cast(
                bf16x8, *(const short8*)&Bs[(wn + ni * 16 + l16) * 32 + quad * 8]);
#pragma unroll
        for (int mi = 0; mi < 4; mi++)
#pragma unroll
            for (int ni = 0; ni < 4; ni++)
                acc[mi][ni] = __builtin_amdgcn_mfma_f32_16x16x32_bf16(
                    a[mi], b[ni], acc[mi][ni], 0, 0, 0);
        __syncthreads();
    }

    // C/D layout: col = lane&15, row = quad*4 + reg (m89/m91-verified)
#pragma unroll
    for (int mi = 0; mi < 4; mi++) {
#pragma unroll
        for (int ni = 0; ni < 4; ni++) {
            long n = n0 + wn + ni * 16 + l16;
            if constexpr (EPI == 4 || EPI == 5) {
                long mb = m0 + wm + mi * 16 + quad * 4;
                ushort4 pk;
#pragma unroll
                for (int r = 0; r < 4; r++) {
                    float v = acc[mi][ni][r];
                    if constexpr (EPI == 5) v = 1.f / (1.f + __expf(-v));
                    ((ushort*)&pk)[r] = f2bf(v);
                }
                *(ushort4*)&outB[n * (long)ldc + mb] = pk;
            } else {
#pragma unroll
                for (int r = 0; r < 4; r++) {
                    long m = m0 + wm + mi * 16 + quad * 4 + r;
                    long idx = m * (long)ldc + n;
                    float v = acc[mi][ni][r];
                    if constexpr (EPI == 0) {
                        outB[idx] = f2bf(v);
                    } else if constexpr (EPI == 1) {
                        outB[idx] = f2bf(1.f / (1.f + __expf(-v)));
                    } else if constexpr (EPI == 2) {
                        float t = fmaxf(v, 0.f);
                        outB[idx] = f2bf(t * t);
                    } else if constexpr (EPI == 3) {
                        outF[idx] = add0[idx] + bf2f(mul0[idx]) * v;
                    }
                }
            }
        }
    }
}

// ---------------------------------------------------------------------------
// Fused LayerNorm + time-shift + mix -> bf16 outputs (2 or 3 mixes).
// ---------------------------------------------------------------------------
template <int NMIX>
__global__ __launch_bounds__(256) void ln_mix(
    const float* __restrict__ x, const float* __restrict__ g,
    const float* __restrict__ be,
    const float* __restrict__ mx0, const float* __restrict__ mx1,
    const float* __restrict__ mx2,
    ushort* __restrict__ o0, ushort* __restrict__ o1, ushort* __restrict__ o2,
    int T, int C) {
    const long row = blockIdx.x;
    const int t = (int)(row % T);
    const int tid = threadIdx.x;
    const int i0 = tid * 4;

    floatx4 xc = *(const floatx4*)&x[row * C + i0];
    floatx4 xp = (floatx4)0.f;
    if (t > 0) xp = *(const floatx4*)&x[(row - 1) * C + i0];

    float sc = xc.x + xc.y + xc.z + xc.w;
    float qc = xc.x * xc.x + xc.y * xc.y + xc.z * xc.z + xc.w * xc.w;
    float sp = xp.x + xp.y + xp.z + xp.w;
    float qp = xp.x * xp.x + xp.y * xp.y + xp.z * xp.z + xp.w * xp.w;

#pragma unroll
    for (int off = 32; off; off >>= 1) {
        sc += __shfl_xor(sc, off);
        qc += __shfl_xor(qc, off);
        sp += __shfl_xor(sp, off);
        qp += __shfl_xor(qp, off);
    }
    __shared__ float part[4][4];
    const int wv = tid >> 6;
    if ((tid & 63) == 0) {
        part[wv][0] = sc; part[wv][1] = qc; part[wv][2] = sp; part[wv][3] = qp;
    }
    __syncthreads();
    sc = part[0][0] + part[1][0] + part[2][0] + part[3][0];
    qc = part[0][1] + part[1][1] + part[2][1] + part[3][1];
    sp = part[0][2] + part[1][2] + part[2][2] + part[3][2];
    qp = part[0][3] + part[1][3] + part[2][3] + part[3][3];

    const float invC = 1.f / (float)C;
    float muc = sc * invC;
    float rsc = rsqrtf(qc * invC - muc * muc + LN_EPS);
    float mup = sp * invC;
    float rsp = rsqrtf(qp * invC - mup * mup + LN_EPS);

    floatx4 gv = *(const floatx4*)&g[i0];
    floatx4 bv = *(const floatx4*)&be[i0];
    floatx4 hc = (xc - muc) * rsc * gv + bv;
    floatx4 hp = (floatx4)0.f;
    if (t > 0) hp = (xp - mup) * rsp * gv + bv;

    {
        floatx4 mk = *(const floatx4*)&mx0[i0];
        floatx4 v = hc * mk + hp * (1.f - mk);
        ushort4 pk;
        pk.x = f2bf(v.x); pk.y = f2bf(v.y); pk.z = f2bf(v.z); pk.w = f2bf(v.w);
        *(ushort4*)&o0[row * C + i0] = pk;
    }
    {
        floatx4 mk = *(const floatx4*)&mx1[i0];
        floatx4 v = hc * mk + hp * (1.f - mk);
        ushort4 pk;
        pk.x = f2bf(v.x); pk.y = f2bf(v.y); pk.z = f2bf(v.z); pk.w = f2bf(v.w);
        *(ushort4*)&o1[row * C + i0] = pk;
    }
    if constexpr (NMIX == 3) {
        floatx4 mk = *(const floatx4*)&mx2[i0];
        floatx4 v = hc * mk + hp * (1.f - mk);
        ushort4 pk;
        pk.x = f2bf(v.x); pk.y = f2bf(v.y); pk.z = f2bf(v.z); pk.w = f2bf(v.w);
        *(ushort4*)&o2[row * C + i0] = pk;
    }
}

// ---------------------------------------------------------------------------
// WKV scan over transposed k/v/r ([C][Mtot] rows, contiguous in t per lane).
// One thread per (b,c); bf16x8 chunk loads with 1-chunk register prefetch.
// Writes ry = r*y in normal [M][C] layout (lane-coalesced scalar stores).
// ---------------------------------------------------------------------------
__global__ __launch_bounds__(64) void wkv_scan_t(
    const float* __restrict__ w, const float* __restrict__ u,
    const ushort* __restrict__ kT, const ushort* __restrict__ vT,
    const ushort* __restrict__ rT, ushort* __restrict__ ry,
    int T, int Mtot, int C) {
    const int gc = blockIdx.x * 64 + threadIdx.x;
    const int b = gc / C;
    const int c = gc - b * C;
    const long rowb = (long)c * Mtot + (long)b * T;
    const ushort* kp = kT + rowb;
    const ushort* vp = vT + rowb;
    const ushort* rp = rT + rowb;
    ushort* op = ry + (long)b * T * C + c;
    const float ww = w[c], uu = u[c];

    float aa = 0.f, pp = -1e38f;
    short8 kc = *(const short8*)kp;
    short8 vc = *(const short8*)vp;
    short8 rc = *(const short8*)rp;
    for (int t0 = 0; t0 < T; t0 += 8) {
        short8 kn, vn, rn;
        if (t0 + 8 < T) {
            kn = *(const short8*)(kp + t0 + 8);
            vn = *(const short8*)(vp + t0 + 8);
            rn = *(const short8*)(rp + t0 + 8);
        }
#pragma unroll
        for (int j = 0; j < 8; ++j) {
            float kk = bf2f((ushort)kc[j]);
            float vv = bf2f((ushort)vc[j]);
            float p = fmaxf(pp, uu + kk);
            float e1 = __expf(pp - p);
            float e2 = __expf(uu + kk - p);
            float y = __fdividef(e1 * aa + e2 * vv, e1 + e2);
            op[(long)(t0 + j) * C] = f2bf(bf2f((ushort)rc[j]) * y);
            float p2 = fmaxf(pp + ww, ww + kk);
            float e1u = __expf(pp + ww - p2);
            float e2u = __expf(ww + kk - p2);
            aa = e1u * aa + e2u * vv;
            pp = p2 + __logf(e1u + e2u);
        }
        kc = kn; vc = vn; rc = rn;
    }
}

// out = x + ry (ry bf16), fully coalesced streaming
__global__ __launch_bounds__(256) void combine_xry(
    const float* __restrict__ x, const ushort* __restrict__ ry,
    float* __restrict__ out) {
    const long i = ((long)blockIdx.x * 256 + threadIdx.x) * 4;
    floatx4 xv = *(const floatx4*)&x[i];
    ushort4 rv = *(const ushort4*)&ry[i];
    floatx4 o;
    o.x = xv.x + bf2f(rv.x);
    o.y = xv.y + bf2f(rv.y);
    o.z = xv.z + bf2f(rv.z);
    o.w = xv.w + bf2f(rv.w);
    *(floatx4*)&out[i] = o;
}

// out[n][k] = bf16(in[k][n]); in is [K][N] fp32 row-major. block (32,8).
__global__ __launch_bounds__(256) void transpose_bf16(
    const float* __restrict__ in, ushort* __restrict__ out, int K, int N) {
    __shared__ float tile[32][33];
    const int tx = threadIdx.x, ty = threadIdx.y;
    const long k0 = (long)blockIdx.y * 32, n0 = (long)blockIdx.x * 32;
#pragma unroll
    for (int i = 0; i < 4; i++)
        tile[ty + i * 8][tx] = in[(k0 + ty + i * 8) * N + n0 + tx];
    __syncthreads();
#pragma unroll
    for (int i = 0; i < 4; i++)
        out[(n0 + ty + i * 8) * K + k0 + tx] = f2bf(tile[tx][ty + i * 8]);
}

extern "C" void kernel_launch(void* const* d_in, const int* in_sizes, int n_in,
                              void* d_out, int out_size, void* d_ws, size_t ws_size,
                              hipStream_t stream) {
    const float* x      = (const float*)d_in[0];
    const float* tdecay = (const float*)d_in[1];
    const float* tfirst = (const float*)d_in[2];
    const float* w_tk   = (const float*)d_in[3];
    const float* w_tv   = (const float*)d_in[4];
    const float* w_tr   = (const float*)d_in[5];
    const float* w_ck   = (const float*)d_in[6];
    const float* w_cv   = (const float*)d_in[7];
    const float* w_cr   = (const float*)d_in[8];
    const float* ln1g   = (const float*)d_in[9];
    const float* ln1b   = (const float*)d_in[10];
    const float* ln2g   = (const float*)d_in[11];
    const float* ln2b   = (const float*)d_in[12];
    const float* mixk   = (const float*)d_in[13];
    const float* mixv   = (const float*)d_in[14];
    const float* mixr   = (const float*)d_in[15];
    const float* cmixk  = (const float*)d_in[16];
    const float* cmixr  = (const float*)d_in[17];
    float* out = (float*)d_out;

    const int C  = in_sizes[1];              // 1024
    const long M = (long)in_sizes[0] / C;    // 16384
    const int T  = 2048;
    const int B  = (int)(M / T);
    const int H  = 2 * C;                    // 2048 = half of 4C

    // workspace layout (MB offsets), lifetime-reused, 184 MB total:
    //  0..24: weights (wT_tk 2, wT_tv 2, wT_tr 2, wT_cr 2, wT_ck 8, wT_cv0 4, wT_cv1 4)
    // 24: xk -> rT -> kkbuf[24..88)
    // 56: xv -> ry
    // 88: xr -> ck
    // 120: kT -> cr
    // 152: vT -> scr
    const size_t MBy = 1024ull * 1024ull;
    char* w8 = (char*)d_ws;
    ushort* wT_tk  = (ushort*)(w8 + 0 * MBy);
    ushort* wT_tv  = (ushort*)(w8 + 2 * MBy);
    ushort* wT_tr  = (ushort*)(w8 + 4 * MBy);
    ushort* wT_cr  = (ushort*)(w8 + 6 * MBy);
    ushort* wT_ck  = (ushort*)(w8 + 8 * MBy);    // [4096][1024]
    ushort* wT_cv0 = (ushort*)(w8 + 16 * MBy);   // [1024][2048]
    ushort* wT_cv1 = (ushort*)(w8 + 20 * MBy);   // [1024][2048]
    ushort* xk     = (ushort*)(w8 + 24 * MBy);
    ushort* xv     = (ushort*)(w8 + 56 * MBy);
    ushort* xr     = (ushort*)(w8 + 88 * MBy);
    ushort* kT     = (ushort*)(w8 + 120 * MBy);  // [C][M]
    ushort* vT     = (ushort*)(w8 + 152 * MBy);  // [C][M]
    ushort* rT     = (ushort*)(w8 + 24 * MBy);   // [C][M], xk dead
    ushort* ry     = (ushort*)(w8 + 56 * MBy);   // [M][C], xv dead
    ushort* ck     = (ushort*)(w8 + 88 * MBy);   // xr dead
    ushort* cr     = (ushort*)(w8 + 120 * MBy);  // kT dead
    ushort* scr    = (ushort*)(w8 + 152 * MBy);  // vT dead
    ushort* kkbuf  = (ushort*)(w8 + 24 * MBy);   // rT/ry... rT dead, 64MB [24,88)

    dim3 tb(32, 8);
    transpose_bf16<<<dim3(C / 32, C / 32), tb, 0, stream>>>(w_tk, wT_tk, C, C);
    transpose_bf16<<<dim3(C / 32, C / 32), tb, 0, stream>>>(w_tv, wT_tv, C, C);
    transpose_bf16<<<dim3(C / 32, C / 32), tb, 0, stream>>>(w_tr, wT_tr, C, C);
    transpose_bf16<<<dim3(C / 32, C / 32), tb, 0, stream>>>(w_cr, wT_cr, C, C);
    transpose_bf16<<<dim3(4 * C / 32, C / 32), tb, 0, stream>>>(w_ck, wT_ck, C, 4 * C);
    transpose_bf16<<<dim3(C / 32, H / 32), tb, 0, stream>>>(w_cv, wT_cv0, H, C);
    transpose_bf16<<<dim3(C / 32, H / 32), tb, 0, stream>>>(w_cv + (long)H * C, wT_cv1, H, C);

    ln_mix<3><<<(int)M, 256, 0, stream>>>(x, ln1g, ln1b, mixk, mixv, mixr,
                                          xk, xv, xr, T, C);

    dim3 gsq(C / 128, (int)(M / 128));
    // k,v,r GEMMs write TRANSPOSED [C][M] for the scan (ldc = M)
    gemm_bt<4><<<gsq, 256, 0, stream>>>(xk, wT_tk, C, C, C, C, (int)M,
                                        nullptr, kT, nullptr, nullptr);
    gemm_bt<4><<<gsq, 256, 0, stream>>>(xv, wT_tv, C, C, C, C, (int)M,
                                        nullptr, vT, nullptr, nullptr);
    gemm_bt<5><<<gsq, 256, 0, stream>>>(xr, wT_tr, C, C, C, C, (int)M,
                                        nullptr, rT, nullptr, nullptr);

    wkv_scan_t<<<(B * C) / 64, 64, 0, stream>>>(tdecay, tfirst, kT, vT, rT,
                                                ry, T, (int)M, C);

    combine_xry<<<(int)((M * C / 4) / 256), 256, 0, stream>>>(x, ry, out);

    ln_mix<2><<<(int)M, 256, 0, stream>>>(out, ln2g, ln2b, cmixk, cmixr, nullptr,
                                          ck, cr, nullptr, T, C);

    gemm_bt<1><<<gsq, 256, 0, stream>>>(cr, wT_cr, C, C, C, C, C,
                                        nullptr, scr, nullptr, nullptr);

    // channel-mix hidden (4C) processed in two 2C halves through one 64MB buffer
    for (int h = 0; h < 2; ++h) {
        const ushort* wck_h = wT_ck + (long)h * H * C;   // rows [h*2C, h*2C+2C)
        const ushort* wcv_h = (h == 0) ? wT_cv0 : wT_cv1;
        gemm_bt<2><<<dim3(H / 128, (int)(M / 128)), 256, 0, stream>>>(
            ck, wck_h, H, C, C, C, H, nullptr, kkbuf, nullptr, nullptr);
        gemm_bt<3><<<gsq, 256, 0, stream>>>(
            kkbuf, wcv_h, C, H, H, H, C, out, nullptr, out, scr);
    }
}